// Round 1
// baseline (5699.720 us; speedup 1.0000x reference)
//
#include <hip/hip_runtime.h>
#include <math.h>

#define N_TOK 131072
#define D 256
#define K_CODES 1024

// ---------------------------------------------------------------- kernel 1
// normalize codebook rows, store TRANSPOSED: cbT[d][k]  (256 x 1024)
__global__ __launch_bounds__(256) void norm_cb_kernel(const float* __restrict__ cb,
                                                      float* __restrict__ cbT) {
  const int c = blockIdx.x;
  const int d = threadIdx.x;
  const float v = cb[(size_t)c * D + d];
  float ss = v * v;
#pragma unroll
  for (int o = 32; o; o >>= 1) ss += __shfl_down(ss, o, 64);
  __shared__ float red[4];
  if ((threadIdx.x & 63) == 0) red[threadIdx.x >> 6] = ss;
  __syncthreads();
  const float tot = red[0] + red[1] + red[2] + red[3];
  const float inv = 1.0f / fmaxf(sqrtf(tot), 1e-12f);
  cbT[(size_t)d * K_CODES + c] = v * inv;
}

// ---------------------------------------------------------------- kernel 2
// per 64-token block: sim GEMM (raw z x cb_n^T), argmax -> codes,
// then atomic dw accumulation of normalized z.
#define FMA4(A, S, B)                                                      \
  A.x = fmaf(S, B.x, A.x);                                                 \
  A.y = fmaf(S, B.y, A.y);                                                 \
  A.z = fmaf(S, B.z, A.z);                                                 \
  A.w = fmaf(S, B.w, A.w);

__global__ __launch_bounds__(256, 1) void vq_assign_kernel(
    const float* __restrict__ z, const float* __restrict__ cbT,
    float* __restrict__ dw, float* __restrict__ out_codes) {
  __shared__ __align__(16) float zl[64 * 256];    // 64 KB, swizzled 16B units
  __shared__ __align__(16) float cbl[256 * 64];   // 64 KB: [k][code-in-chunk]
  __shared__ float invn[64];
  __shared__ float candv[16][64];
  __shared__ int candi[16][64];
  __shared__ int codesl[64];

  const int tid = threadIdx.x;
  const int wv = tid >> 6;
  const int ln = tid & 63;
  const int tg = tid & 15;   // token group: tokens 4*tg..4*tg+3
  const int cg = tid >> 4;   // code group: codes (in chunk) 4*cg..4*cg+3
  const size_t t0 = (size_t)blockIdx.x * 64;

  // stage z tile: logical (r,k4) lives at phys 16B-unit r*64 + (k4 ^ ((r>>2)&15))
  // (dest linear per lane, source pre-swizzled -> balanced banks both sides)
#pragma unroll
  for (int i = 0; i < 16; ++i) {
    const int r = wv * 16 + i;
    const int swz = (r >> 2) & 15;
    const float4 v = *(const float4*)(z + (t0 + r) * D + 4 * (ln ^ swz));
    *(float4*)(&zl[(r * 64 + ln) * 4]) = v;
  }
  __syncthreads();

  // per-row inverse norms (argmax is scale-invariant; norms only feed dw)
  for (int i = 0; i < 16; ++i) {
    const int r = wv * 16 + i;
    const float4 v = *(const float4*)(&zl[(r * 64 + ln) * 4]);
    float ss = v.x * v.x + v.y * v.y + v.z * v.z + v.w * v.w;
#pragma unroll
    for (int o = 32; o; o >>= 1) ss += __shfl_down(ss, o, 64);
    if (ln == 0) invn[r] = 1.0f / fmaxf(sqrtf(ss), 1e-12f);
  }

  float bv[4];
  int bi[4];
#pragma unroll
  for (int j = 0; j < 4; ++j) {
    bv[j] = -3.4e38f;
    bi[j] = 0;
  }

  for (int cc = 0; cc < 16; ++cc) {
    __syncthreads();
    // stage cb chunk [256 k][64 codes]
#pragma unroll
    for (int u = 0; u < 16; ++u) {
      const int idx = u * 256 + tid;
      const int k = idx >> 4, m = idx & 15;
      *(float4*)(&cbl[k * 64 + 4 * m]) =
          *(const float4*)(cbT + (size_t)k * K_CODES + cc * 64 + 4 * m);
    }
    __syncthreads();

    float4 acc[4];
    const float4 zero4 = {0.f, 0.f, 0.f, 0.f};
#pragma unroll
    for (int j = 0; j < 4; ++j) acc[j] = zero4;

#pragma unroll 4
    for (int k4p = 0; k4p < 64; ++k4p) {
      const int k4 = k4p ^ tg;  // logical k4 at sequential phys unit k4p
      float4 a4[4];
#pragma unroll
      for (int j = 0; j < 4; ++j)
        a4[j] = *(const float4*)(&zl[((4 * tg + j) * 64 + k4p) * 4]);
      const float* bbase = &cbl[k4 * 256 + 4 * cg];  // k = 4*k4+kk rows
      const float4 b0 = *(const float4*)(bbase);
      const float4 b1 = *(const float4*)(bbase + 64);
      const float4 b2 = *(const float4*)(bbase + 128);
      const float4 b3 = *(const float4*)(bbase + 192);
#pragma unroll
      for (int j = 0; j < 4; ++j) {
        FMA4(acc[j], a4[j].x, b0)
        FMA4(acc[j], a4[j].y, b1)
        FMA4(acc[j], a4[j].z, b2)
        FMA4(acc[j], a4[j].w, b3)
      }
    }

    // running best; strict > keeps earliest (lowest) code on exact ties
    const int cbase = cc * 64 + cg * 4;
#pragma unroll
    for (int j = 0; j < 4; ++j) {
      if (acc[j].x > bv[j]) { bv[j] = acc[j].x; bi[j] = cbase + 0; }
      if (acc[j].y > bv[j]) { bv[j] = acc[j].y; bi[j] = cbase + 1; }
      if (acc[j].z > bv[j]) { bv[j] = acc[j].z; bi[j] = cbase + 2; }
      if (acc[j].w > bv[j]) { bv[j] = acc[j].w; bi[j] = cbase + 3; }
    }
  }

  __syncthreads();
#pragma unroll
  for (int j = 0; j < 4; ++j) {
    candv[cg][4 * tg + j] = bv[j];
    candi[cg][4 * tg + j] = bi[j];
  }
  __syncthreads();
  if (tid < 64) {
    float v = candv[0][tid];
    int idx = candi[0][tid];
#pragma unroll
    for (int c = 1; c < 16; ++c) {
      const float v2 = candv[c][tid];
      const int i2 = candi[c][tid];
      if (v2 > v || (v2 == v && i2 < idx)) { v = v2; idx = i2; }
    }
    codesl[tid] = idx;
    out_codes[t0 + tid] = (float)idx;
  }
  __syncthreads();

  // dw[code[r]] += z_n[r]: wave wv owns rows r = 4*i+wv, lanes cover 16B units
  for (int i = 0; i < 16; ++i) {
    const int r = 4 * i + wv;
    const int code = codesl[r];
    const float s = invn[r];
    const float4 v = *(const float4*)(&zl[(r * 64 + ln) * 4]);
    const int k4 = ln ^ ((r >> 2) & 15);
    float* p = dw + (size_t)code * D + 4 * k4;
    unsafeAtomicAdd(p + 0, v.x * s);
    unsafeAtomicAdd(p + 1, v.y * s);
    unsafeAtomicAdd(p + 2, v.z * s);
    unsafeAtomicAdd(p + 3, v.w * s);
  }
}

// ---------------------------------------------------------------- kernel 3
// embed[k] = l2norm(0.97*ema_w[k] + 0.03*dw[k])   (cluster_size cancels)
__global__ __launch_bounds__(256) void ema_embed_kernel(const float* __restrict__ ema_w,
                                                        const float* __restrict__ dw,
                                                        float* __restrict__ embed) {
  const int c = blockIdx.x;
  const int d = threadIdx.x;
  const size_t idx = (size_t)c * D + d;
  const float w = 0.97f * ema_w[idx] + 0.03f * dw[idx];
  float ss = w * w;
#pragma unroll
  for (int o = 32; o; o >>= 1) ss += __shfl_down(ss, o, 64);
  __shared__ float red[4];
  if ((d & 63) == 0) red[d >> 6] = ss;
  __syncthreads();
  const float tot = red[0] + red[1] + red[2] + red[3];
  embed[idx] = w / fmaxf(sqrtf(tot), 1e-12f);
}

// ---------------------------------------------------------------- kernel 4
// z_q_out = embed[codes];  loss partial = sum (z_e - z_q)^2
__global__ __launch_bounds__(256) void gather_loss_kernel(
    const float* __restrict__ z, const float* __restrict__ embed,
    const float* __restrict__ codesf, float* __restrict__ out0,
    double* __restrict__ loss) {
  const size_t u0 = (size_t)blockIdx.x * 4096 + threadIdx.x;
  float part = 0.f;
  for (int i = 0; i < 16; ++i) {
    const size_t u = u0 + (size_t)i * 256;
    const size_t t = u >> 6;
    const int k4 = (int)(u & 63);
    const int code = (int)codesf[t];
    const float4 e = *(const float4*)(embed + (size_t)code * D + 4 * k4);
    const float4 ze = *(const float4*)(z + t * D + 4 * k4);
    *(float4*)(out0 + t * D + 4 * k4) = e;
    const float dx = ze.x - e.x, dy = ze.y - e.y;
    const float dz = ze.z - e.z, dw4 = ze.w - e.w;
    part += dx * dx + dy * dy + dz * dz + dw4 * dw4;
  }
#pragma unroll
  for (int o = 32; o; o >>= 1) part += __shfl_down(part, o, 64);
  __shared__ float red[4];
  if ((threadIdx.x & 63) == 0) red[threadIdx.x >> 6] = part;
  __syncthreads();
  if (threadIdx.x == 0)
    unsafeAtomicAdd(loss, (double)(red[0] + red[1] + red[2] + red[3]));
}

// ---------------------------------------------------------------- kernel 5
__global__ void finalize_kernel(const double* __restrict__ loss,
                                float* __restrict__ out2) {
  out2[0] = (float)(0.25 * loss[0] / (double)(33554432.0));
}

// ---------------------------------------------------------------- launcher
extern "C" void kernel_launch(void* const* d_in, const int* in_sizes, int n_in,
                              void* d_out, int out_size, void* d_ws, size_t ws_size,
                              hipStream_t stream) {
  const float* z = (const float*)d_in[0];        // [131072,256]
  const float* cb = (const float*)d_in[1];       // [1024,256]
  const float* ema_w = (const float*)d_in[3];    // [1024,256]

  float* out0 = (float*)d_out;                           // z_q_out [131072*256]
  float* out1 = out0 + (size_t)N_TOK * D;                // codes   [131072]
  float* out2 = out1 + N_TOK;                            // vq_loss [1]

  char* ws = (char*)d_ws;
  float* cbT = (float*)ws;                       // 1 MB: [256][1024]
  float* dw = (float*)(ws + (1u << 20));         // 1 MB: [1024][256]
  float* embed = (float*)(ws + (2u << 20));      // 1 MB: [1024][256]
  double* loss = (double*)(ws + (3u << 20));     // 8 B

  hipMemsetAsync(dw, 0, (size_t)K_CODES * D * sizeof(float), stream);
  hipMemsetAsync(loss, 0, sizeof(double), stream);

  norm_cb_kernel<<<K_CODES, 256, 0, stream>>>(cb, cbT);
  vq_assign_kernel<<<N_TOK / 64, 256, 0, stream>>>(z, cbT, dw, out1);
  ema_embed_kernel<<<K_CODES, 256, 0, stream>>>(ema_w, dw, embed);
  gather_loss_kernel<<<N_TOK * D / 4096 / 256, 256, 0, stream>>>(z, embed, out1, out0, loss);
  finalize_kernel<<<1, 1, 0, stream>>>(loss, out2);
}